// Round 12
// baseline (1034.224 us; speedup 1.0000x reference)
//
#include <hip/hip_runtime.h>
#include <math.h>

#define B 8
#define LSEQ 2500
#define EDIM 100
#define DDIM 128
#define YLAB 8921
#define KW 9
#define BYTOT (B*YLAB)   // 71368
#define LP 2560          // padded L (20*128)
#define NLBS 20          // l-blocks of 128 in k_sums
#define NYB 70           // y-blocks of 128 in k_sums
#define NPB 140          // y-blocks of 64 in k_pool
#define LPOOL 2528       // pool: 79 tiles of 32 (l >= LSEQ handled by zero pads)

typedef __attribute__((ext_vector_type(8))) short bf16x8;
typedef __attribute__((ext_vector_type(4))) float f32x4;

__device__ __forceinline__ ushort f2bf(float f){
    union { float f; unsigned u; } v; v.f = f;
    unsigned r = v.u + 0x7FFFu + ((v.u >> 16) & 1u);
    return (ushort)(r >> 16);
}
__device__ __forceinline__ float bf2f(ushort u){
    union { unsigned u; float f; } v; v.u = ((unsigned)u) << 16;
    return v.f;
}

// ---- ws float offsets ----
#define OFF_HB 0                 // hb bf16 [B][LP][128] : 1,310,720 fl
#define OFF_HT 1310720           // hT bf16 [B][128][LP] : 1,310,720 fl
#define OFF_UB 2621440           // U bf16 [Y][128]      : 570,944 fl
#define OFF_PS 3192384           // psum [NLBS][B*Y]     : 1,427,360 fl
#define OFF_LG 4691112           // logits [B*Y]
#define OFF_LSP 4762480          // loss partials [128]
#define OFF_WT 4762608           // conv wT 115,200 fl -> end ~19.5 MB

// ---------------- prep
#define NP1 (DDIM*EDIM*KW)          // 115200
#define NP2 (YLAB*DDIM)             // 1141888
#define NP3 (B*DDIM*(LP-LSEQ))      // 61440
#define NP4 (B*(LP-LSEQ)*DDIM)      // 61440
__global__ __launch_bounds__(256) void k_prep(const float* __restrict__ w, const float* __restrict__ U,
                                              float* __restrict__ wT, ushort* __restrict__ Ub,
                                              ushort* __restrict__ hT, ushort* __restrict__ hb){
    int i = blockIdx.x * 256 + threadIdx.x;
    if (i < NP1) {
        int k = i % KW, e = (i / KW) % EDIM, d = i / (KW * EDIM);
        wT[(k * EDIM + e) * DDIM + d] = w[i];
    }
    int i2 = i - NP1;
    if (i2 >= 0 && i2 < NP2) Ub[i2] = f2bf(U[i2]);
    int i3 = i - NP1 - NP2;
    if (i3 >= 0 && i3 < NP3) {
        int c = i3 % (LP - LSEQ), bd = i3 / (LP - LSEQ);
        hT[(size_t)bd * LP + LSEQ + c] = 0;
    }
    int i4 = i - NP1 - NP2 - NP3;
    if (i4 >= 0 && i4 < NP4) {
        int b = i4 / ((LP - LSEQ) * DDIM);
        int r = i4 % ((LP - LSEQ) * DDIM);
        int l = LSEQ + r / DDIM, d = r % DDIM;
        hb[((size_t)b * LP + l) * DDIM + d] = 0;
    }
}

// ---------------- fused embed + conv1d + tanh
#define CTL 20
__global__ __launch_bounds__(256) void k_conv(const int* __restrict__ x, const float* __restrict__ emb,
                                              const float* __restrict__ wT, const float* __restrict__ bias,
                                              ushort* __restrict__ hb, ushort* __restrict__ hT) {
    __shared__ float se[EDIM * 32];
    __shared__ ushort hstage[DDIM][CTL + 2];
    int blk = blockIdx.x;
    int b = blk / (LSEQ / CTL);
    int l0 = (blk % (LSEQ / CTL)) * CTL;
    int tid = threadIdx.x;
    for (int i = tid; i < (CTL + 8) * EDIM; i += 256) {
        int row = i / EDIM, e = i - row * EDIM;
        int l = l0 + row - 4;
        float v = 0.f;
        if (l >= 0 && l < LSEQ) {
            int tok = x[b * LSEQ + l];
            v = emb[(size_t)tok * EDIM + e];
        }
        se[e * 32 + row] = v;
    }
    __syncthreads();
    int d = tid & 127;
    int g = tid >> 7;
    float bv = bias[d];
    float acc[10];
#pragma unroll
    for (int li = 0; li < 10; li++) acc[li] = bv;
    for (int e = 0; e < EDIM; e++) {
        float r[20];
#pragma unroll
        for (int t2 = 0; t2 < 10; t2++) {
            float2 rr = *(const float2*)&se[e * 32 + g * 10 + 2 * t2];
            r[2 * t2] = rr.x; r[2 * t2 + 1] = rr.y;
        }
#pragma unroll
        for (int k = 0; k < KW; k++) {
            float wv = wT[(k * EDIM + e) * DDIM + d];
#pragma unroll
            for (int li = 0; li < 10; li++) acc[li] += r[li + k] * wv;
        }
    }
#pragma unroll
    for (int li = 0; li < 10; li++) {
        int l = l0 + g * 10 + li;
        ushort u = f2bf(tanhf(acc[li]));
        hb[((size_t)b * LP + l) * DDIM + d] = u;
        hstage[d][g * 10 + li] = u;
    }
    __syncthreads();
    int d2 = tid >> 1, half = tid & 1;
    size_t base = ((size_t)b * DDIM + d2) * LP + l0 + half * 10;
#pragma unroll
    for (int q = 0; q < 10; q++) hT[base + q] = hstage[d2][half * 10 + q];
}

// ---------------- sums via swapped MFMA: lane owns its y-column. No LDS, no barriers.
__global__ __launch_bounds__(256) void k_sums(const ushort* __restrict__ hb, const ushort* __restrict__ Ub,
                                              float* __restrict__ psum) {
    int wg = blockIdx.x;
    int b = wg & 7;
    int r = wg >> 3;
    int lblk = r % NLBS, yblk = r / NLBS;
    int l0 = lblk * 128, y0 = yblk * 128;
    int tid = threadIdx.x, w = tid >> 6, lane = tid & 63, g = lane >> 4, ln = lane & 15;
    int y0w = y0 + w * 32;
    bf16x8 zf = {0, 0, 0, 0, 0, 0, 0, 0};
    bf16x8 au[2][4];
    bool vya[2];
#pragma unroll
    for (int yg = 0; yg < 2; yg++) {
        int y = y0w + yg * 16 + ln;
        vya[yg] = y < YLAB;
        const ushort* Ap = Ub + (size_t)(vya[yg] ? y : 0) * DDIM + g * 8;
#pragma unroll
        for (int kk = 0; kk < 4; kk++) au[yg][kk] = vya[yg] ? *(const bf16x8*)(Ap + kk * 32) : zf;
    }
    const ushort* hbB = hb + (size_t)b * LP * DDIM;
    f32x4 zero4 = {0.f, 0.f, 0.f, 0.f};
    float ts[2] = {0.f, 0.f};
#pragma unroll
    for (int lt = 0; lt < 4; lt++) {
        int lw = l0 + lt * 32;
        bf16x8 a[2][4];
#pragma unroll
        for (int fl = 0; fl < 2; fl++)
#pragma unroll
            for (int kk = 0; kk < 4; kk++)
                a[fl][kk] = *(const bf16x8*)(hbB + (size_t)(lw + fl * 16 + ln) * DDIM + kk * 32 + g * 8);
        f32x4 sc[2][2];
        sc[0][0] = zero4; sc[0][1] = zero4; sc[1][0] = zero4; sc[1][1] = zero4;
#pragma unroll
        for (int kk = 0; kk < 4; kk++)
#pragma unroll
            for (int fl = 0; fl < 2; fl++) {
                sc[0][fl] = __builtin_amdgcn_mfma_f32_16x16x32_bf16(a[fl][kk], au[0][kk], sc[0][fl], 0, 0, 0);
                sc[1][fl] = __builtin_amdgcn_mfma_f32_16x16x32_bf16(a[fl][kk], au[1][kk], sc[1][fl], 0, 0, 0);
            }
        // C: row l = lw + fl*16 + g*4 + j ; col y = y0w + yg*16 + ln
#pragma unroll
        for (int yg = 0; yg < 2; yg++)
#pragma unroll
            for (int fl = 0; fl < 2; fl++) {
                int lb = lw + fl * 16 + g * 4;
#pragma unroll
                for (int j = 0; j < 4; j++)
                    ts[yg] += (lb + j < LSEQ) ? __expf(sc[yg][fl][j]) : 0.f;
            }
    }
#pragma unroll
    for (int yg = 0; yg < 2; yg++) {
        float t = ts[yg];
        t += __shfl_xor(t, 16, 64);
        t += __shfl_xor(t, 32, 64);
        if (g == 0 && vya[yg])
            psum[(size_t)lblk * BYTOT + b * YLAB + y0w + yg * 16 + ln] = t;
    }
}

// ---------------- barrier-free fused pool: direct-global operands, per-wave et only
__global__ __launch_bounds__(256) void k_pool(const ushort* __restrict__ hb, const ushort* __restrict__ hT,
                                              const ushort* __restrict__ Ub, const float* __restrict__ psum,
                                              const float* __restrict__ fw, const float* __restrict__ fb,
                                              float* __restrict__ alpha, float* __restrict__ yhat,
                                              float* __restrict__ logits) {
    __shared__ ushort et[4][16 * 44];    // per-wave bf16 alpha tile [y 16][l 32, stride 44]
    int wg = blockIdx.x;
    int b = wg & 7;
    int y0 = (wg >> 3) * 64;
    int tid = threadIdx.x, w = tid >> 6, lane = tid & 63, g = lane >> 4, ln = lane & 15;
    int y0w = y0 + w * 16;
    bf16x8 zf = {0, 0, 0, 0, 0, 0, 0, 0};
    int ya = y0w + ln;
    bool vya = ya < YLAB;
    const ushort* Ap = Ub + (size_t)(vya ? ya : 0) * DDIM + g * 8;
    bf16x8 au[4];
#pragma unroll
    for (int kk = 0; kk < 4; kk++) au[kk] = vya ? *(const bf16x8*)(Ap + kk * 32) : zf;
    // per-lane rinv for y = ya (no shared table, no barrier)
    float rvl = 0.f;
    if (vya) {
        float s = 0.f;
#pragma unroll
        for (int j = 0; j < NLBS; j++) s += psum[(size_t)j * BYTOT + b * YLAB + ya];
        rvl = 1.f / s;
    }
    f32x4 zero4 = {0.f, 0.f, 0.f, 0.f};
    f32x4 accm[8];
#pragma unroll
    for (int fd = 0; fd < 8; fd++) accm[fd] = zero4;

    const ushort* hbB = hb + (size_t)b * LP * DDIM;
    const ushort* htB = hT + (size_t)b * DDIM * LP;
    float* aB = alpha + (size_t)b * YLAB * LSEQ;

    for (int l0 = 0; l0 < LPOOL; l0 += 32) {
        // score B-frags direct from global (L2-resident hb)
        bf16x8 hbf[2][4];
#pragma unroll
        for (int fl = 0; fl < 2; fl++)
#pragma unroll
            for (int kk = 0; kk < 4; kk++)
                hbf[fl][kk] = *(const bf16x8*)(hbB + (size_t)(l0 + fl * 16 + ln) * DDIM + kk * 32 + g * 8);
        // scores swapped: sc[fl][j] = s[y=y0w+ln][l=l0+fl*16+g*4+j]
        f32x4 sc[2];
        sc[0] = zero4; sc[1] = zero4;
#pragma unroll
        for (int kk = 0; kk < 4; kk++)
#pragma unroll
            for (int fl = 0; fl < 2; fl++)
                sc[fl] = __builtin_amdgcn_mfma_f32_16x16x32_bf16(hbf[fl][kk], au[kk], sc[fl], 0, 0, 0);
        // exp*rinv -> et (bf16): alpha tile = pool A-frag (same-wave LDS, lgkm wait only)
#pragma unroll
        for (int fl = 0; fl < 2; fl++) {
            float an0 = __expf(sc[fl][0]) * rvl;
            float an1 = __expf(sc[fl][1]) * rvl;
            float an2 = __expf(sc[fl][2]) * rvl;
            float an3 = __expf(sc[fl][3]) * rvl;
            unsigned long long pk =
                (unsigned long long)f2bf(an0) | ((unsigned long long)f2bf(an1) << 16) |
                ((unsigned long long)f2bf(an2) << 32) | ((unsigned long long)f2bf(an3) << 48);
            *(unsigned long long*)&et[w][ln * 44 + fl * 16 + g * 4] = pk;
        }
        // pool MFMA: A = et row (lane-own y), B = hT rows direct from global (L2-resident)
        bf16x8 af = *(const bf16x8*)&et[w][ln * 44 + g * 8];
#pragma unroll
        for (int fd = 0; fd < 8; fd++) {
            bf16x8 bt = *(const bf16x8*)(htB + (size_t)(fd * 16 + ln) * LP + l0 + g * 8);
            accm[fd] = __builtin_amdgcn_mfma_f32_16x16x32_bf16(af, bt, accm[fd], 0, 0, 0);
        }
        // alpha store from bf16 tile: 16 insts, each 2 rows x 128B contiguous
        if (l0 + 32 <= LSEQ) {
#pragma unroll
            for (int i = 0; i < 8; i++) {
                int r = i * 2 + (lane >> 5);
                int c = lane & 31;
                int y = y0w + r;
                if (y < YLAB) aB[(size_t)y * LSEQ + l0 + c] = bf2f(et[w][r * 44 + c]);
            }
        } else if (l0 < LSEQ) {
#pragma unroll
            for (int i = 0; i < 8; i++) {
                int r = i * 2 + (lane >> 5);
                int c = lane & 31;
                int y = y0w + r;
                int l = l0 + c;
                if (y < YLAB && l < LSEQ) aB[(size_t)y * LSEQ + l] = bf2f(et[w][r * 44 + c]);
            }
        }
    }
    // fused logits epilogue: accm[fd][j] = m[y0w+g*4+j][fd*16+ln] (rinv already in et)
    float lp[4] = {0.f, 0.f, 0.f, 0.f};
#pragma unroll
    for (int j = 0; j < 4; j++) {
        int yr = y0w + g * 4 + j;
        bool vr = yr < YLAB;
#pragma unroll
        for (int fd = 0; fd < 8; fd++) {
            float fwv = vr ? fw[(size_t)yr * DDIM + fd * 16 + ln] : 0.f;
            lp[j] += accm[fd][j] * fwv;
        }
    }
#pragma unroll
    for (int j = 0; j < 4; j++) {
        float t = lp[j];
        t += __shfl_xor(t, 1, 64); t += __shfl_xor(t, 2, 64);
        t += __shfl_xor(t, 4, 64); t += __shfl_xor(t, 8, 64);
        lp[j] = t;
    }
    if (ln == 0) {
#pragma unroll
        for (int j = 0; j < 4; j++) {
            int yr = y0w + g * 4 + j;
            if (yr < YLAB) {
                float lg = lp[j] + fb[yr];
                int idx = b * YLAB + yr;
                logits[idx] = lg;
                yhat[idx] = 1.f / (1.f + expf(-lg));
            }
        }
    }
}

// ---------------- BCE partials + finalize
__global__ __launch_bounds__(256) void k_loss1(const float* __restrict__ logits, const float* __restrict__ target,
                                               float* __restrict__ partials) {
    int tid = threadIdx.x;
    int base = blockIdx.x * 1024;
    float sum = 0.f;
#pragma unroll
    for (int q = 0; q < 4; q++) {
        int i = base + q * 256 + tid;
        if (i < BYTOT) {
            float z = logits[i], t = target[i];
            sum += fmaxf(z, 0.f) - z * t + log1pf(expf(-fabsf(z)));
        }
    }
    for (int o = 32; o > 0; o >>= 1) sum += __shfl_down(sum, o, 64);
    __shared__ float red[4];
    if ((tid & 63) == 0) red[tid >> 6] = sum;
    __syncthreads();
    if (tid == 0) partials[blockIdx.x] = red[0] + red[1] + red[2] + red[3];
}

__global__ __launch_bounds__(128) void k_loss2(const float* __restrict__ partials, float* __restrict__ out_loss) {
    int tid = threadIdx.x;
    float s = (tid < 70) ? partials[tid] : 0.f;
    for (int o = 32; o > 0; o >>= 1) s += __shfl_down(s, o, 64);
    __shared__ float red[2];
    if ((tid & 63) == 0) red[tid >> 6] = s;
    __syncthreads();
    if (tid == 0) out_loss[0] = (red[0] + red[1]) / (float)BYTOT;
}

extern "C" void kernel_launch(void* const* d_in, const int* in_sizes, int n_in,
                              void* d_out, int out_size, void* d_ws, size_t ws_size,
                              hipStream_t stream) {
    const int* x = (const int*)d_in[0];
    const float* target = (const float*)d_in[1];
    const float* emb = (const float*)d_in[2];
    const float* conv_w = (const float*)d_in[3];
    const float* conv_b = (const float*)d_in[4];
    const float* U = (const float*)d_in[5];
    const float* fw = (const float*)d_in[6];
    const float* fb = (const float*)d_in[7];

    float* out = (float*)d_out;
    float* yhat = out;
    float* loss = out + BYTOT;
    float* alpha = out + BYTOT + 1;

    float* ws = (float*)d_ws;
    ushort* hb = (ushort*)(ws + OFF_HB);
    ushort* hT = (ushort*)(ws + OFF_HT);
    ushort* Ub = (ushort*)(ws + OFF_UB);
    float* psum = ws + OFF_PS;
    float* logits = ws + OFF_LG;
    float* lpart = ws + OFF_LSP;
    float* wT = ws + OFF_WT;

    k_prep<<<(NP1 + NP2 + NP3 + NP4 + 255) / 256, 256, 0, stream>>>(conv_w, U, wT, Ub, hT, hb);
    k_conv<<<B * (LSEQ / CTL), 256, 0, stream>>>(x, emb, wT, conv_b, hb, hT);
    k_sums<<<NYB * NLBS * B, 256, 0, stream>>>(hb, Ub, psum);
    k_pool<<<NPB * B, 256, 0, stream>>>(hb, hT, Ub, psum, fw, fb, alpha, yhat, logits);
    k_loss1<<<70, 256, 0, stream>>>(logits, target, lpart);
    k_loss2<<<1, 128, 0, stream>>>(lpart, loss);
}

// Round 13
// 721.453 us; speedup vs baseline: 1.4335x; 1.4335x over previous
//
#include <hip/hip_runtime.h>
#include <math.h>

#define B 8
#define LSEQ 2500
#define EDIM 100
#define DDIM 128
#define YLAB 8921
#define KW 9
#define BYTOT (B*YLAB)   // 71368
#define LP 2560          // padded L (20*128)
#define NLBS 20          // l-blocks of 128 in k_sums
#define NYB 70           // y-blocks of 128 in k_sums
#define NPBY 70          // y-blocks of 128 in k_pool

typedef __attribute__((ext_vector_type(8))) short bf16x8;
typedef __attribute__((ext_vector_type(8))) unsigned short u16x8;
typedef __attribute__((ext_vector_type(4))) float f32x4;

__device__ __forceinline__ ushort f2bf(float f){
    union { float f; unsigned u; } v; v.f = f;
    unsigned r = v.u + 0x7FFFu + ((v.u >> 16) & 1u);
    return (ushort)(r >> 16);
}
__device__ __forceinline__ float bf2f(ushort u){
    union { unsigned u; float f; } v; v.u = ((unsigned)u) << 16;
    return v.f;
}

// ---- ws float offsets ----
#define OFF_HB 0                 // hb bf16 [B][LP][128] : 1,310,720 fl
#define OFF_HT 1310720           // hT bf16 [B][128][LP] : 1,310,720 fl
#define OFF_UB 2621440           // U bf16 [Y][128]      : 570,944 fl
#define OFF_PS 3192384           // psum [NLBS][B*Y]     : 1,427,360 fl
#define OFF_RI 4619744           // rinv [B*Y]
#define OFF_LG 4691112           // logits [B*Y]
#define OFF_LSP 4762480          // loss partials [128]
#define OFF_WT 4762608           // conv wT 115,200 fl -> end ~19.5 MB

// ---------------- prep
#define NP1 (DDIM*EDIM*KW)          // 115200
#define NP2 (YLAB*DDIM)             // 1141888
#define NP3 (B*DDIM*(LP-LSEQ))      // 61440
#define NP4 (B*(LP-LSEQ)*DDIM)      // 61440
__global__ __launch_bounds__(256) void k_prep(const float* __restrict__ w, const float* __restrict__ U,
                                              float* __restrict__ wT, ushort* __restrict__ Ub,
                                              ushort* __restrict__ hT, ushort* __restrict__ hb){
    int i = blockIdx.x * 256 + threadIdx.x;
    if (i < NP1) {
        int k = i % KW, e = (i / KW) % EDIM, d = i / (KW * EDIM);
        wT[(k * EDIM + e) * DDIM + d] = w[i];
    }
    int i2 = i - NP1;
    if (i2 >= 0 && i2 < NP2) Ub[i2] = f2bf(U[i2]);
    int i3 = i - NP1 - NP2;
    if (i3 >= 0 && i3 < NP3) {
        int c = i3 % (LP - LSEQ), bd = i3 / (LP - LSEQ);
        hT[(size_t)bd * LP + LSEQ + c] = 0;
    }
    int i4 = i - NP1 - NP2 - NP3;
    if (i4 >= 0 && i4 < NP4) {
        int b = i4 / ((LP - LSEQ) * DDIM);
        int r = i4 % ((LP - LSEQ) * DDIM);
        int l = LSEQ + r / DDIM, d = r % DDIM;
        hb[((size_t)b * LP + l) * DDIM + d] = 0;
    }
}

// ---------------- fused embed + conv1d + tanh
#define CTL 20
__global__ __launch_bounds__(256) void k_conv(const int* __restrict__ x, const float* __restrict__ emb,
                                              const float* __restrict__ wT, const float* __restrict__ bias,
                                              ushort* __restrict__ hb, ushort* __restrict__ hT) {
    __shared__ float se[EDIM * 32];
    __shared__ ushort hstage[DDIM][CTL + 2];
    int blk = blockIdx.x;
    int b = blk / (LSEQ / CTL);
    int l0 = (blk % (LSEQ / CTL)) * CTL;
    int tid = threadIdx.x;
    for (int i = tid; i < (CTL + 8) * EDIM; i += 256) {
        int row = i / EDIM, e = i - row * EDIM;
        int l = l0 + row - 4;
        float v = 0.f;
        if (l >= 0 && l < LSEQ) {
            int tok = x[b * LSEQ + l];
            v = emb[(size_t)tok * EDIM + e];
        }
        se[e * 32 + row] = v;
    }
    __syncthreads();
    int d = tid & 127;
    int g = tid >> 7;
    float bv = bias[d];
    float acc[10];
#pragma unroll
    for (int li = 0; li < 10; li++) acc[li] = bv;
    for (int e = 0; e < EDIM; e++) {
        float r[20];
#pragma unroll
        for (int t2 = 0; t2 < 10; t2++) {
            float2 rr = *(const float2*)&se[e * 32 + g * 10 + 2 * t2];
            r[2 * t2] = rr.x; r[2 * t2 + 1] = rr.y;
        }
#pragma unroll
        for (int k = 0; k < KW; k++) {
            float wv = wT[(k * EDIM + e) * DDIM + d];
#pragma unroll
            for (int li = 0; li < 10; li++) acc[li] += r[li + k] * wv;
        }
    }
#pragma unroll
    for (int li = 0; li < 10; li++) {
        int l = l0 + g * 10 + li;
        ushort u = f2bf(tanhf(acc[li]));
        hb[((size_t)b * LP + l) * DDIM + d] = u;
        hstage[d][g * 10 + li] = u;
    }
    __syncthreads();
    int d2 = tid >> 1, half = tid & 1;
    size_t base = ((size_t)b * DDIM + d2) * LP + l0 + half * 10;
#pragma unroll
    for (int q = 0; q < 10; q++) hT[base + q] = hstage[d2][half * 10 + q];
}

// ---------------- softmax sums via MFMA: 128y x 128l blocks, XCD-swizzled
__global__ __launch_bounds__(256) void k_sums(const ushort* __restrict__ hb, const ushort* __restrict__ Ub,
                                              float* __restrict__ psum) {
    int wg = blockIdx.x;
    int b = wg & 7;
    int r = wg >> 3;
    int lblk = r % NLBS, yblk = r / NLBS;
    int l0 = lblk * 128, y0 = yblk * 128;
    int tid = threadIdx.x, w = tid >> 6, lane = tid & 63, g = lane >> 4, ln = lane & 15;
    int h = w >> 1, lh = w & 1;
    int y0w = y0 + h * 64;
    bf16x8 zf = {0, 0, 0, 0, 0, 0, 0, 0};
    bf16x8 au[4][4];
    bool vya[4];
#pragma unroll
    for (int yf = 0; yf < 4; yf++) {
        int ya = y0w + yf * 16 + ln;
        vya[yf] = ya < YLAB;
        const ushort* Ap = Ub + (size_t)(vya[yf] ? ya : 0) * DDIM + g * 8;
#pragma unroll
        for (int kk = 0; kk < 4; kk++) au[yf][kk] = vya[yf] ? *(const bf16x8*)(Ap + kk * 32) : zf;
    }
    f32x4 zero4 = {0.f, 0.f, 0.f, 0.f};
    const ushort* hbB = hb + (size_t)b * LP * DDIM;
    float ts[4][4] = {};
#pragma unroll
    for (int lt = 0; lt < 2; lt++) {
        int lw = l0 + (lt * 2 + lh) * 32;
        f32x4 acc[4][2];
#pragma unroll
        for (int yf = 0; yf < 4; yf++) { acc[yf][0] = zero4; acc[yf][1] = zero4; }
#pragma unroll
        for (int kk = 0; kk < 4; kk++) {
            bf16x8 bv0 = *(const bf16x8*)(hbB + (size_t)(lw + ln) * DDIM + kk * 32 + g * 8);
            bf16x8 bv1 = *(const bf16x8*)(hbB + (size_t)(lw + 16 + ln) * DDIM + kk * 32 + g * 8);
#pragma unroll
            for (int yf = 0; yf < 4; yf++) {
                acc[yf][0] = __builtin_amdgcn_mfma_f32_16x16x32_bf16(au[yf][kk], bv0, acc[yf][0], 0, 0, 0);
                acc[yf][1] = __builtin_amdgcn_mfma_f32_16x16x32_bf16(au[yf][kk], bv1, acc[yf][1], 0, 0, 0);
            }
        }
#pragma unroll
        for (int yf = 0; yf < 4; yf++)
#pragma unroll
            for (int fl = 0; fl < 2; fl++)
#pragma unroll
                for (int j = 0; j < 4; j++) {
                    int y = y0w + yf * 16 + g * 4 + j;
                    int l = lw + fl * 16 + ln;
                    bool v = (y < YLAB) && (l < LSEQ);
                    ts[yf][j] += v ? __expf(acc[yf][fl][j]) : 0.f;
                }
    }
#pragma unroll
    for (int yf = 0; yf < 4; yf++)
#pragma unroll
        for (int j = 0; j < 4; j++) {
            float t = ts[yf][j];
            t += __shfl_xor(t, 1, 64); t += __shfl_xor(t, 2, 64);
            t += __shfl_xor(t, 4, 64); t += __shfl_xor(t, 8, 64);
            ts[yf][j] = t;
        }
    __shared__ float psl[2][128];
    if (ln == 0) {
#pragma unroll
        for (int yf = 0; yf < 4; yf++)
#pragma unroll
            for (int j = 0; j < 4; j++)
                psl[lh][h * 64 + yf * 16 + g * 4 + j] = ts[yf][j];
    }
    __syncthreads();
    if (tid < 128) {
        int y = y0 + tid;
        if (y < YLAB) psum[(size_t)lblk * BYTOT + b * YLAB + y] = psl[0][tid] + psl[1][tid];
    }
}

// ---------------- rinv
__global__ __launch_bounds__(256) void k_rinv(const float* __restrict__ psum, float* __restrict__ rinv) {
    int i = blockIdx.x * 256 + threadIdx.x;
    if (i >= BYTOT) return;
    float s = 0.f;
#pragma unroll
    for (int j = 0; j < NLBS; j++) s += psum[(size_t)j * BYTOT + i];
    rinv[i] = 1.f / s;
}

// ---------------- fused pool: staged tiles, 32 y per wave (128 y/block) for 2x LDS-read amortization
__global__ __launch_bounds__(256) void k_pool(const ushort* __restrict__ hb, const ushort* __restrict__ hT,
                                              const ushort* __restrict__ Ub, const float* __restrict__ rinv,
                                              const float* __restrict__ fw, const float* __restrict__ fb,
                                              float* __restrict__ alpha, float* __restrict__ yhat,
                                              float* __restrict__ logits) {
    __shared__ ushort hbs[32 * 128];     // 8 KB
    __shared__ ushort hts[128 * 40];     // 10 KB
    __shared__ ushort et[4][32 * 44];    // 11 KB (bf16 alpha tile = pool A-frag)
    int wg = blockIdx.x;
    int b = wg & 7;
    int y0 = (wg >> 3) * 128;
    int tid = threadIdx.x, w = tid >> 6, lane = tid & 63, g = lane >> 4, ln = lane & 15;
    int y0w = y0 + w * 32;
    bf16x8 zf = {0, 0, 0, 0, 0, 0, 0, 0};
    bf16x8 au[2][4];
    float rvl[2];
    bool vya[2];
#pragma unroll
    for (int yf = 0; yf < 2; yf++) {
        int ya = y0w + yf * 16 + ln;
        vya[yf] = ya < YLAB;
        const ushort* Ap = Ub + (size_t)(vya[yf] ? ya : 0) * DDIM + g * 8;
#pragma unroll
        for (int kk = 0; kk < 4; kk++) au[yf][kk] = vya[yf] ? *(const bf16x8*)(Ap + kk * 32) : zf;
        rvl[yf] = vya[yf] ? rinv[b * YLAB + ya] : 0.f;
    }
    f32x4 zero4 = {0.f, 0.f, 0.f, 0.f};
    f32x4 accm[2][8];
#pragma unroll
    for (int yf = 0; yf < 2; yf++)
#pragma unroll
        for (int fd = 0; fd < 8; fd++) accm[yf][fd] = zero4;

    int s0 = tid, s1 = tid + 256;
    const ushort* hbB = hb + (size_t)b * LP * DDIM;
    const ushort* htB = hT + (size_t)b * DDIM * LP;
    int l_a = s0 >> 4, sg_a = s0 & 15, l_b = s1 >> 4, sg_b = s1 & 15;
    int d_a = s0 >> 2, q_a = s0 & 3, d_b = s1 >> 2, q_b = s1 & 3;
    int wsg_a = sg_a ^ (l_a & 7), wsg_b = sg_b ^ (l_b & 7);
    u16x8 rhb0, rhb1, rht0, rht1;
    rhb0 = *(const u16x8*)(hbB + (size_t)l_a * DDIM + sg_a * 8);
    rhb1 = *(const u16x8*)(hbB + (size_t)l_b * DDIM + sg_b * 8);
    rht0 = *(const u16x8*)(htB + (size_t)d_a * LP + q_a * 8);
    rht1 = *(const u16x8*)(htB + (size_t)d_b * LP + q_b * 8);

    float* aB = alpha + (size_t)b * YLAB * LSEQ;

    for (int l0 = 0; l0 < LP; l0 += 32) {
        *(u16x8*)&hbs[l_a * DDIM + wsg_a * 8] = rhb0;
        *(u16x8*)&hbs[l_b * DDIM + wsg_b * 8] = rhb1;
        *(u16x8*)&hts[d_a * 40 + q_a * 8] = rht0;
        *(u16x8*)&hts[d_b * 40 + q_b * 8] = rht1;
        __syncthreads();
        if (l0 + 32 < LP) {
            int ln0 = l0 + 32;
            rhb0 = *(const u16x8*)(hbB + (size_t)(ln0 + l_a) * DDIM + sg_a * 8);
            rhb1 = *(const u16x8*)(hbB + (size_t)(ln0 + l_b) * DDIM + sg_b * 8);
            rht0 = *(const u16x8*)(htB + (size_t)d_a * LP + ln0 + q_a * 8);
            rht1 = *(const u16x8*)(htB + (size_t)d_b * LP + ln0 + q_b * 8);
        }
        // scores swapped: sc[yf][fl][j] = s[y=y0w+yf*16+ln][l=l0+fl*16+g*4+j]
        f32x4 sc[2][2];
        sc[0][0] = zero4; sc[0][1] = zero4; sc[1][0] = zero4; sc[1][1] = zero4;
#pragma unroll
        for (int kk = 0; kk < 4; kk++)
#pragma unroll
            for (int fl = 0; fl < 2; fl++) {
                int lrow = fl * 16 + ln;
                int slotr = (kk * 4 + g) ^ (lrow & 7);
                bf16x8 bv = *(const bf16x8*)&hbs[lrow * DDIM + slotr * 8];
                sc[0][fl] = __builtin_amdgcn_mfma_f32_16x16x32_bf16(bv, au[0][kk], sc[0][fl], 0, 0, 0);
                sc[1][fl] = __builtin_amdgcn_mfma_f32_16x16x32_bf16(bv, au[1][kk], sc[1][fl], 0, 0, 0);
            }
        // exp*rinv -> et (bf16)
#pragma unroll
        for (int yf = 0; yf < 2; yf++)
#pragma unroll
            for (int fl = 0; fl < 2; fl++) {
                float an0 = __expf(sc[yf][fl][0]) * rvl[yf];
                float an1 = __expf(sc[yf][fl][1]) * rvl[yf];
                float an2 = __expf(sc[yf][fl][2]) * rvl[yf];
                float an3 = __expf(sc[yf][fl][3]) * rvl[yf];
                unsigned long long pk =
                    (unsigned long long)f2bf(an0) | ((unsigned long long)f2bf(an1) << 16) |
                    ((unsigned long long)f2bf(an2) << 32) | ((unsigned long long)f2bf(an3) << 48);
                *(unsigned long long*)&et[w][(yf * 16 + ln) * 44 + fl * 16 + g * 4] = pk;
            }
        // pool MFMA: bt amortized over 2 y-frags
        bf16x8 af0 = *(const bf16x8*)&et[w][ln * 44 + g * 8];
        bf16x8 af1 = *(const bf16x8*)&et[w][(16 + ln) * 44 + g * 8];
#pragma unroll
        for (int fd = 0; fd < 8; fd++) {
            bf16x8 bt = *(const bf16x8*)&hts[(fd * 16 + ln) * 40 + g * 8];
            accm[0][fd] = __builtin_amdgcn_mfma_f32_16x16x32_bf16(af0, bt, accm[0][fd], 0, 0, 0);
            accm[1][fd] = __builtin_amdgcn_mfma_f32_16x16x32_bf16(af1, bt, accm[1][fd], 0, 0, 0);
        }
        // alpha store from bf16 tile: 16 insts, each 2 rows x 128B
        if (l0 + 32 <= LSEQ) {
#pragma unroll
            for (int i = 0; i < 16; i++) {
                int r = i * 2 + (lane >> 5);
                int c = lane & 31;
                int y = y0w + r;
                if (y < YLAB) aB[(size_t)y * LSEQ + l0 + c] = bf2f(et[w][r * 44 + c]);
            }
        } else if (l0 < LSEQ) {
#pragma unroll
            for (int i = 0; i < 16; i++) {
                int r = i * 2 + (lane >> 5);
                int c = lane & 31;
                int y = y0w + r;
                int l = l0 + c;
                if (y < YLAB && l < LSEQ) aB[(size_t)y * LSEQ + l] = bf2f(et[w][r * 44 + c]);
            }
        }
        __syncthreads();
    }
    // fused logits epilogue (accm already rinv-scaled via et)
#pragma unroll
    for (int yf = 0; yf < 2; yf++) {
        float lp[4] = {0.f, 0.f, 0.f, 0.f};
#pragma unroll
        for (int j = 0; j < 4; j++) {
            int yr = y0w + yf * 16 + g * 4 + j;
            bool vr = yr < YLAB;
#pragma unroll
            for (int fd = 0; fd < 8; fd++) {
                float fwv = vr ? fw[(size_t)yr * DDIM + fd * 16 + ln] : 0.f;
                lp[j] += accm[yf][fd][j] * fwv;
            }
        }
#pragma unroll
        for (int j = 0; j < 4; j++) {
            float t = lp[j];
            t += __shfl_xor(t, 1, 64); t += __shfl_xor(t, 2, 64);
            t += __shfl_xor(t, 4, 64); t += __shfl_xor(t, 8, 64);
            lp[j] = t;
        }
        if (ln == 0) {
#pragma unroll
            for (int j = 0; j < 4; j++) {
                int yr = y0w + yf * 16 + g * 4 + j;
                if (yr < YLAB) {
                    float lg = lp[j] + fb[yr];
                    int idx = b * YLAB + yr;
                    logits[idx] = lg;
                    yhat[idx] = 1.f / (1.f + expf(-lg));
                }
            }
        }
    }
}

// ---------------- BCE partials + finalize
__global__ __launch_bounds__(256) void k_loss1(const float* __restrict__ logits, const float* __restrict__ target,
                                               float* __restrict__ partials) {
    int tid = threadIdx.x;
    int base = blockIdx.x * 1024;
    float sum = 0.f;
#pragma unroll
    for (int q = 0; q < 4; q++) {
        int i = base + q * 256 + tid;
        if (i < BYTOT) {
            float z = logits[i], t = target[i];
            sum += fmaxf(z, 0.f) - z * t + log1pf(expf(-fabsf(z)));
        }
    }
    for (int o = 32; o > 0; o >>= 1) sum += __shfl_down(sum, o, 64);
    __shared__ float red[4];
    if ((tid & 63) == 0) red[tid >> 6] = sum;
    __syncthreads();
    if (tid == 0) partials[blockIdx.x] = red[0] + red[1] + red[2] + red[3];
}

__global__ __launch_bounds__(128) void k_loss2(const float* __restrict__ partials, float* __restrict__ out_loss) {
    int tid = threadIdx.x;
    float s = (tid < 70) ? partials[tid] : 0.f;
    for (int o = 32; o > 0; o >>= 1) s += __shfl_down(s, o, 64);
    __shared__ float red[2];
    if ((tid & 63) == 0) red[tid >> 6] = s;
    __syncthreads();
    if (tid == 0) out_loss[0] = (red[0] + red[1]) / (float)BYTOT;
}

extern "C" void kernel_launch(void* const* d_in, const int* in_sizes, int n_in,
                              void* d_out, int out_size, void* d_ws, size_t ws_size,
                              hipStream_t stream) {
    const int* x = (const int*)d_in[0];
    const float* target = (const float*)d_in[1];
    const float* emb = (const float*)d_in[2];
    const float* conv_w = (const float*)d_in[3];
    const float* conv_b = (const float*)d_in[4];
    const float* U = (const float*)d_in[5];
    const float* fw = (const float*)d_in[6];
    const float* fb = (const float*)d_in[7];

    float* out = (float*)d_out;
    float* yhat = out;
    float* loss = out + BYTOT;
    float* alpha = out + BYTOT + 1;

    float* ws = (float*)d_ws;
    ushort* hb = (ushort*)(ws + OFF_HB);
    ushort* hT = (ushort*)(ws + OFF_HT);
    ushort* Ub = (ushort*)(ws + OFF_UB);
    float* psum = ws + OFF_PS;
    float* rinv = ws + OFF_RI;
    float* logits = ws + OFF_LG;
    float* lpart = ws + OFF_LSP;
    float* wT = ws + OFF_WT;

    k_prep<<<(NP1 + NP2 + NP3 + NP4 + 255) / 256, 256, 0, stream>>>(conv_w, U, wT, Ub, hT, hb);
    k_conv<<<B * (LSEQ / CTL), 256, 0, stream>>>(x, emb, wT, conv_b, hb, hT);
    k_sums<<<NYB * NLBS * B, 256, 0, stream>>>(hb, Ub, psum);
    k_rinv<<<(BYTOT + 255) / 256, 256, 0, stream>>>(psum, rinv);
    k_pool<<<NPBY * B, 256, 0, stream>>>(hb, hT, Ub, rinv, fw, fb, alpha, yhat, logits);
    k_loss1<<<70, 256, 0, stream>>>(logits, target, lpart);
    k_loss2<<<1, 128, 0, stream>>>(lpart, loss);
}

// Round 14
// 634.874 us; speedup vs baseline: 1.6290x; 1.1364x over previous
//
#include <hip/hip_runtime.h>
#include <math.h>

#define B 8
#define LSEQ 2500
#define EDIM 100
#define DDIM 128
#define YLAB 8921
#define KW 9
#define BYTOT (B*YLAB)   // 71368
#define LP 2560          // padded L (80*32, 20*128)
#define NLBS 20          // l-blocks of 128 in k_sums
#define NYB 70           // y-blocks of 128 in k_sums
#define NPB 140          // y-blocks of 64 in k_pool

typedef __attribute__((ext_vector_type(8))) short bf16x8;
typedef __attribute__((ext_vector_type(8))) unsigned short u16x8;
typedef __attribute__((ext_vector_type(4))) float f32x4;

__device__ __forceinline__ ushort f2bf(float f){
    union { float f; unsigned u; } v; v.f = f;
    unsigned r = v.u + 0x7FFFu + ((v.u >> 16) & 1u);
    return (ushort)(r >> 16);
}
__device__ __forceinline__ float bf2f(ushort u){
    union { unsigned u; float f; } v; v.u = ((unsigned)u) << 16;
    return v.f;
}

// ---- ws float offsets ----
#define OFF_HB 0                 // hb bf16 [B][LP][128] : 1,310,720 fl
#define OFF_HT 1310720           // hT bf16 [B][128][LP] : 1,310,720 fl
#define OFF_UB 2621440           // U bf16 [Y][128]      : 570,944 fl
#define OFF_PS 3192384           // psum [NLBS][B*Y]     : 1,427,360 fl
#define OFF_RI 4619744           // rinv [B*Y]
#define OFF_LG 4691112           // logits [B*Y]
#define OFF_LSP 4762480          // loss partials [128]
#define OFF_WT 4762608           // conv wT 115,200 fl -> end ~19.5 MB

// ---------------- prep
#define NP1 (DDIM*EDIM*KW)          // 115200
#define NP2 (YLAB*DDIM)             // 1141888
#define NP3 (B*DDIM*(LP-LSEQ))      // 61440
#define NP4 (B*(LP-LSEQ)*DDIM)      // 61440
__global__ __launch_bounds__(256) void k_prep(const float* __restrict__ w, const float* __restrict__ U,
                                              float* __restrict__ wT, ushort* __restrict__ Ub,
                                              ushort* __restrict__ hT, ushort* __restrict__ hb){
    int i = blockIdx.x * 256 + threadIdx.x;
    if (i < NP1) {
        int k = i % KW, e = (i / KW) % EDIM, d = i / (KW * EDIM);
        wT[(k * EDIM + e) * DDIM + d] = w[i];
    }
    int i2 = i - NP1;
    if (i2 >= 0 && i2 < NP2) Ub[i2] = f2bf(U[i2]);
    int i3 = i - NP1 - NP2;
    if (i3 >= 0 && i3 < NP3) {
        int c = i3 % (LP - LSEQ), bd = i3 / (LP - LSEQ);
        hT[(size_t)bd * LP + LSEQ + c] = 0;
    }
    int i4 = i - NP1 - NP2 - NP3;
    if (i4 >= 0 && i4 < NP4) {
        int b = i4 / ((LP - LSEQ) * DDIM);
        int r = i4 % ((LP - LSEQ) * DDIM);
        int l = LSEQ + r / DDIM, d = r % DDIM;
        hb[((size_t)b * LP + l) * DDIM + d] = 0;
    }
}

// ---------------- fused embed + conv1d + tanh
#define CTL 20
__global__ __launch_bounds__(256) void k_conv(const int* __restrict__ x, const float* __restrict__ emb,
                                              const float* __restrict__ wT, const float* __restrict__ bias,
                                              ushort* __restrict__ hb, ushort* __restrict__ hT) {
    __shared__ float se[EDIM * 32];
    __shared__ ushort hstage[DDIM][CTL + 2];
    int blk = blockIdx.x;
    int b = blk / (LSEQ / CTL);
    int l0 = (blk % (LSEQ / CTL)) * CTL;
    int tid = threadIdx.x;
    for (int i = tid; i < (CTL + 8) * EDIM; i += 256) {
        int row = i / EDIM, e = i - row * EDIM;
        int l = l0 + row - 4;
        float v = 0.f;
        if (l >= 0 && l < LSEQ) {
            int tok = x[b * LSEQ + l];
            v = emb[(size_t)tok * EDIM + e];
        }
        se[e * 32 + row] = v;
    }
    __syncthreads();
    int d = tid & 127;
    int g = tid >> 7;
    float bv = bias[d];
    float acc[10];
#pragma unroll
    for (int li = 0; li < 10; li++) acc[li] = bv;
    for (int e = 0; e < EDIM; e++) {
        float r[20];
#pragma unroll
        for (int t2 = 0; t2 < 10; t2++) {
            float2 rr = *(const float2*)&se[e * 32 + g * 10 + 2 * t2];
            r[2 * t2] = rr.x; r[2 * t2 + 1] = rr.y;
        }
#pragma unroll
        for (int k = 0; k < KW; k++) {
            float wv = wT[(k * EDIM + e) * DDIM + d];
#pragma unroll
            for (int li = 0; li < 10; li++) acc[li] += r[li + k] * wv;
        }
    }
#pragma unroll
    for (int li = 0; li < 10; li++) {
        int l = l0 + g * 10 + li;
        ushort u = f2bf(tanhf(acc[li]));
        hb[((size_t)b * LP + l) * DDIM + d] = u;
        hstage[d][g * 10 + li] = u;
    }
    __syncthreads();
    int d2 = tid >> 1, half = tid & 1;
    size_t base = ((size_t)b * DDIM + d2) * LP + l0 + half * 10;
#pragma unroll
    for (int q = 0; q < 10; q++) hT[base + q] = hstage[d2][half * 10 + q];
}

// ---------------- softmax sums via MFMA: 128y x 128l blocks, XCD-swizzled
__global__ __launch_bounds__(256) void k_sums(const ushort* __restrict__ hb, const ushort* __restrict__ Ub,
                                              float* __restrict__ psum) {
    int wg = blockIdx.x;
    int b = wg & 7;
    int r = wg >> 3;
    int lblk = r % NLBS, yblk = r / NLBS;
    int l0 = lblk * 128, y0 = yblk * 128;
    int tid = threadIdx.x, w = tid >> 6, lane = tid & 63, g = lane >> 4, ln = lane & 15;
    int h = w >> 1, lh = w & 1;
    int y0w = y0 + h * 64;
    bf16x8 zf = {0, 0, 0, 0, 0, 0, 0, 0};
    bf16x8 au[4][4];
    bool vya[4];
#pragma unroll
    for (int yf = 0; yf < 4; yf++) {
        int ya = y0w + yf * 16 + ln;
        vya[yf] = ya < YLAB;
        const ushort* Ap = Ub + (size_t)(vya[yf] ? ya : 0) * DDIM + g * 8;
#pragma unroll
        for (int kk = 0; kk < 4; kk++) au[yf][kk] = vya[yf] ? *(const bf16x8*)(Ap + kk * 32) : zf;
    }
    f32x4 zero4 = {0.f, 0.f, 0.f, 0.f};
    const ushort* hbB = hb + (size_t)b * LP * DDIM;
    float ts[4][4] = {};
#pragma unroll
    for (int lt = 0; lt < 2; lt++) {
        int lw = l0 + (lt * 2 + lh) * 32;
        f32x4 acc[4][2];
#pragma unroll
        for (int yf = 0; yf < 4; yf++) { acc[yf][0] = zero4; acc[yf][1] = zero4; }
#pragma unroll
        for (int kk = 0; kk < 4; kk++) {
            bf16x8 bv0 = *(const bf16x8*)(hbB + (size_t)(lw + ln) * DDIM + kk * 32 + g * 8);
            bf16x8 bv1 = *(const bf16x8*)(hbB + (size_t)(lw + 16 + ln) * DDIM + kk * 32 + g * 8);
#pragma unroll
            for (int yf = 0; yf < 4; yf++) {
                acc[yf][0] = __builtin_amdgcn_mfma_f32_16x16x32_bf16(au[yf][kk], bv0, acc[yf][0], 0, 0, 0);
                acc[yf][1] = __builtin_amdgcn_mfma_f32_16x16x32_bf16(au[yf][kk], bv1, acc[yf][1], 0, 0, 0);
            }
        }
#pragma unroll
        for (int yf = 0; yf < 4; yf++)
#pragma unroll
            for (int fl = 0; fl < 2; fl++)
#pragma unroll
                for (int j = 0; j < 4; j++) {
                    int y = y0w + yf * 16 + g * 4 + j;
                    int l = lw + fl * 16 + ln;
                    bool v = (y < YLAB) && (l < LSEQ);
                    ts[yf][j] += v ? __expf(acc[yf][fl][j]) : 0.f;
                }
    }
#pragma unroll
    for (int yf = 0; yf < 4; yf++)
#pragma unroll
        for (int j = 0; j < 4; j++) {
            float t = ts[yf][j];
            t += __shfl_xor(t, 1, 64); t += __shfl_xor(t, 2, 64);
            t += __shfl_xor(t, 4, 64); t += __shfl_xor(t, 8, 64);
            ts[yf][j] = t;
        }
    __shared__ float psl[2][128];
    if (ln == 0) {
#pragma unroll
        for (int yf = 0; yf < 4; yf++)
#pragma unroll
            for (int j = 0; j < 4; j++)
                psl[lh][h * 64 + yf * 16 + g * 4 + j] = ts[yf][j];
    }
    __syncthreads();
    if (tid < 128) {
        int y = y0 + tid;
        if (y < YLAB) psum[(size_t)lblk * BYTOT + b * YLAB + y] = psl[0][tid] + psl[1][tid];
    }
}

// ---------------- rinv
__global__ __launch_bounds__(256) void k_rinv(const float* __restrict__ psum, float* __restrict__ rinv) {
    int i = blockIdx.x * 256 + threadIdx.x;
    if (i >= BYTOT) return;
    float s = 0.f;
#pragma unroll
    for (int j = 0; j < NLBS; j++) s += psum[(size_t)j * BYTOT + i];
    rinv[i] = 1.f / s;
}

// ---------------- fused pool: staged scores + alpha (bf16->f32 store from et) + pool MFMA + logits
__global__ __launch_bounds__(256) void k_pool(const ushort* __restrict__ hb, const ushort* __restrict__ hT,
                                              const ushort* __restrict__ Ub, const float* __restrict__ rinv,
                                              const float* __restrict__ fw, const float* __restrict__ fb,
                                              float* __restrict__ alpha, float* __restrict__ yhat,
                                              float* __restrict__ logits) {
    __shared__ ushort hbs[32 * 128];     // 8 KB
    __shared__ ushort hts[128 * 40];     // 10 KB
    __shared__ ushort et[4][16 * 44];    // 5.5 KB  (bf16 alpha tile, also pool A-frag)
    int wg = blockIdx.x;
    int b = wg & 7;
    int y0 = (wg >> 3) * 64;
    int tid = threadIdx.x, w = tid >> 6, lane = tid & 63, g = lane >> 4, ln = lane & 15;
    int y0w = y0 + w * 16;
    bf16x8 zf = {0, 0, 0, 0, 0, 0, 0, 0};
    int ya = y0w + ln;
    bool vya = ya < YLAB;
    const ushort* Ap = Ub + (size_t)(vya ? ya : 0) * DDIM + g * 8;
    bf16x8 au[4];
#pragma unroll
    for (int kk = 0; kk < 4; kk++) au[kk] = vya ? *(const bf16x8*)(Ap + kk * 32) : zf;
    float rvl = vya ? rinv[b * YLAB + ya] : 0.f;
    f32x4 zero4 = {0.f, 0.f, 0.f, 0.f};
    f32x4 accm[8];
#pragma unroll
    for (int fd = 0; fd < 8; fd++) accm[fd] = zero4;

    int s0 = tid, s1 = tid + 256;
    const ushort* hbB = hb + (size_t)b * LP * DDIM;
    const ushort* htB = hT + (size_t)b * DDIM * LP;
    int l_a = s0 >> 4, sg_a = s0 & 15, l_b = s1 >> 4, sg_b = s1 & 15;
    int d_a = s0 >> 2, q_a = s0 & 3, d_b = s1 >> 2, q_b = s1 & 3;
    int wsg_a = sg_a ^ (l_a & 7), wsg_b = sg_b ^ (l_b & 7);
    u16x8 rhb0, rhb1, rht0, rht1;
    rhb0 = *(const u16x8*)(hbB + (size_t)l_a * DDIM + sg_a * 8);
    rhb1 = *(const u16x8*)(hbB + (size_t)l_b * DDIM + sg_b * 8);
    rht0 = *(const u16x8*)(htB + (size_t)d_a * LP + q_a * 8);
    rht1 = *(const u16x8*)(htB + (size_t)d_b * LP + q_b * 8);

    float* aB = alpha + (size_t)b * YLAB * LSEQ;

    for (int l0 = 0; l0 < LP; l0 += 32) {
        *(u16x8*)&hbs[l_a * DDIM + wsg_a * 8] = rhb0;
        *(u16x8*)&hbs[l_b * DDIM + wsg_b * 8] = rhb1;
        *(u16x8*)&hts[d_a * 40 + q_a * 8] = rht0;
        *(u16x8*)&hts[d_b * 40 + q_b * 8] = rht1;
        __syncthreads();
        if (l0 + 32 < LP) {
            int ln0 = l0 + 32;
            rhb0 = *(const u16x8*)(hbB + (size_t)(ln0 + l_a) * DDIM + sg_a * 8);
            rhb1 = *(const u16x8*)(hbB + (size_t)(ln0 + l_b) * DDIM + sg_b * 8);
            rht0 = *(const u16x8*)(htB + (size_t)d_a * LP + ln0 + q_a * 8);
            rht1 = *(const u16x8*)(htB + (size_t)d_b * LP + ln0 + q_b * 8);
        }
        // scores swapped: sc[fl][j] = s[y=y0w+ln][l=l0+fl*16+g*4+j]
        f32x4 sc[2];
        sc[0] = zero4; sc[1] = zero4;
#pragma unroll
        for (int kk = 0; kk < 4; kk++)
#pragma unroll
            for (int fl = 0; fl < 2; fl++) {
                int lrow = fl * 16 + ln;
                int slotr = (kk * 4 + g) ^ (lrow & 7);
                bf16x8 bv = *(const bf16x8*)&hbs[lrow * DDIM + slotr * 8];
                sc[fl] = __builtin_amdgcn_mfma_f32_16x16x32_bf16(bv, au[kk], sc[fl], 0, 0, 0);
            }
        // exp*rinv -> et (bf16): both the alpha tile and the pool A-frag
#pragma unroll
        for (int fl = 0; fl < 2; fl++) {
            float an0 = __expf(sc[fl][0]) * rvl;
            float an1 = __expf(sc[fl][1]) * rvl;
            float an2 = __expf(sc[fl][2]) * rvl;
            float an3 = __expf(sc[fl][3]) * rvl;
            unsigned long long pk =
                (unsigned long long)f2bf(an0) | ((unsigned long long)f2bf(an1) << 16) |
                ((unsigned long long)f2bf(an2) << 32) | ((unsigned long long)f2bf(an3) << 48);
            *(unsigned long long*)&et[w][ln * 44 + fl * 16 + g * 4] = pk;
        }
        // pool MFMA
        bf16x8 af = *(const bf16x8*)&et[w][ln * 44 + g * 8];
#pragma unroll
        for (int fd = 0; fd < 8; fd++) {
            bf16x8 bt = *(const bf16x8*)&hts[(fd * 16 + ln) * 40 + g * 8];
            accm[fd] = __builtin_amdgcn_mfma_f32_16x16x32_bf16(af, bt, accm[fd], 0, 0, 0);
        }
        // alpha store from bf16 tile: 8 insts, 2 rows x 128B
        if (l0 + 32 <= LSEQ) {
#pragma unroll
            for (int i = 0; i < 8; i++) {
                int r = i * 2 + (lane >> 5);
                int c = lane & 31;
                int y = y0w + r;
                if (y < YLAB) aB[(size_t)y * LSEQ + l0 + c] = bf2f(et[w][r * 44 + c]);
            }
        } else if (l0 < LSEQ) {
#pragma unroll
            for (int i = 0; i < 8; i++) {
                int r = i * 2 + (lane >> 5);
                int c = lane & 31;
                int y = y0w + r;
                int l = l0 + c;
                if (y < YLAB && l < LSEQ) aB[(size_t)y * LSEQ + l] = bf2f(et[w][r * 44 + c]);
            }
        }
        __syncthreads();
    }
    // fused logits epilogue
    float lp[4] = {0.f, 0.f, 0.f, 0.f};
#pragma unroll
    for (int j = 0; j < 4; j++) {
        int yr = y0w + g * 4 + j;
        bool vr = yr < YLAB;
#pragma unroll
        for (int fd = 0; fd < 8; fd++) {
            float fwv = vr ? fw[(size_t)yr * DDIM + fd * 16 + ln] : 0.f;
            lp[j] += accm[fd][j] * fwv;
        }
    }
#pragma unroll
    for (int j = 0; j < 4; j++) {
        float t = lp[j];
        t += __shfl_xor(t, 1, 64); t += __shfl_xor(t, 2, 64);
        t += __shfl_xor(t, 4, 64); t += __shfl_xor(t, 8, 64);
        lp[j] = t;
    }
    if (ln == 0) {
#pragma unroll
        for (int j = 0; j < 4; j++) {
            int yr = y0w + g * 4 + j;
            if (yr < YLAB) {
                float lg = lp[j] + fb[yr];
                int idx = b * YLAB + yr;
                logits[idx] = lg;
                yhat[idx] = 1.f / (1.f + expf(-lg));
            }
        }
    }
}

// ---------------- BCE partials (70 blocks) + finalize
__global__ __launch_bounds__(256) void k_loss1(const float* __restrict__ logits, const float* __restrict__ target,
                                               float* __restrict__ partials) {
    int tid = threadIdx.x;
    int base = blockIdx.x * 1024;
    float sum = 0.f;
#pragma unroll
    for (int q = 0; q < 4; q++) {
        int i = base + q * 256 + tid;
        if (i < BYTOT) {
            float z = logits[i], t = target[i];
            sum += fmaxf(z, 0.f) - z * t + log1pf(expf(-fabsf(z)));
        }
    }
    for (int o = 32; o > 0; o >>= 1) sum += __shfl_down(sum, o, 64);
    __shared__ float red[4];
    if ((tid & 63) == 0) red[tid >> 6] = sum;
    __syncthreads();
    if (tid == 0) partials[blockIdx.x] = red[0] + red[1] + red[2] + red[3];
}

__global__ __launch_bounds__(128) void k_loss2(const float* __restrict__ partials, float* __restrict__ out_loss) {
    int tid = threadIdx.x;
    float s = (tid < 70) ? partials[tid] : 0.f;
    for (int o = 32; o > 0; o >>= 1) s += __shfl_down(s, o, 64);
    __shared__ float red[2];
    if ((tid & 63) == 0) red[tid >> 6] = s;
    __syncthreads();
    if (tid == 0) out_loss[0] = (red[0] + red[1]) / (float)BYTOT;
}

extern "C" void kernel_launch(void* const* d_in, const int* in_sizes, int n_in,
                              void* d_out, int out_size, void* d_ws, size_t ws_size,
                              hipStream_t stream) {
    const int* x = (const int*)d_in[0];
    const float* target = (const float*)d_in[1];
    const float* emb = (const float*)d_in[2];
    const float* conv_w = (const float*)d_in[3];
    const float* conv_b = (const float*)d_in[4];
    const float* U = (const float*)d_in[5];
    const float* fw = (const float*)d_in[6];
    const float* fb = (const float*)d_in[7];

    float* out = (float*)d_out;
    float* yhat = out;
    float* loss = out + BYTOT;
    float* alpha = out + BYTOT + 1;

    float* ws = (float*)d_ws;
    ushort* hb = (ushort*)(ws + OFF_HB);
    ushort* hT = (ushort*)(ws + OFF_HT);
    ushort* Ub = (ushort*)(ws + OFF_UB);
    float* psum = ws + OFF_PS;
    float* rinv = ws + OFF_RI;
    float* logits = ws + OFF_LG;
    float* lpart = ws + OFF_LSP;
    float* wT = ws + OFF_WT;

    k_prep<<<(NP1 + NP2 + NP3 + NP4 + 255) / 256, 256, 0, stream>>>(conv_w, U, wT, Ub, hT, hb);
    k_conv<<<B * (LSEQ / CTL), 256, 0, stream>>>(x, emb, wT, conv_b, hb, hT);
    k_sums<<<NYB * NLBS * B, 256, 0, stream>>>(hb, Ub, psum);
    k_rinv<<<(BYTOT + 255) / 256, 256, 0, stream>>>(psum, rinv);
    k_pool<<<NPB * B, 256, 0, stream>>>(hb, hT, Ub, rinv, fw, fb, alpha, yhat, logits);
    k_loss1<<<70, 256, 0, stream>>>(logits, target, lpart);
    k_loss2<<<1, 128, 0, stream>>>(lpart, loss);
}

// Round 15
// 631.314 us; speedup vs baseline: 1.6382x; 1.0056x over previous
//
#include <hip/hip_runtime.h>
#include <math.h>

#define B 8
#define LSEQ 2500
#define EDIM 100
#define DDIM 128
#define YLAB 8921
#define KW 9
#define BYTOT (B*YLAB)   // 71368
#define LP 2560          // padded L (80*32, 20*128)
#define NLBS 20          // l-blocks of 128 in k_sums
#define NYB 70           // y-blocks of 128 in k_sums
#define NPB 140          // y-blocks of 64 in k_pool

typedef __attribute__((ext_vector_type(8))) short bf16x8;
typedef __attribute__((ext_vector_type(8))) unsigned short u16x8;
typedef __attribute__((ext_vector_type(4))) float f32x4;

__device__ __forceinline__ ushort f2bf(float f){
    union { float f; unsigned u; } v; v.f = f;
    unsigned r = v.u + 0x7FFFu + ((v.u >> 16) & 1u);
    return (ushort)(r >> 16);
}
__device__ __forceinline__ float bf2f(ushort u){
    union { unsigned u; float f; } v; v.u = ((unsigned)u) << 16;
    return v.f;
}

// ---- ws float offsets ----
#define OFF_HB 0                 // hb bf16 [B][LP][128] : 1,310,720 fl
#define OFF_HT 1310720           // hT bf16 [B][128][LP] : 1,310,720 fl
#define OFF_UB 2621440           // U bf16 [Y][128]      : 570,944 fl
#define OFF_PS 3192384           // psum [NLBS][B*Y]     : 1,427,360 fl
#define OFF_RI 4619744           // rinv [B*Y]
#define OFF_LG 4691112           // logits [B*Y]
#define OFF_LSP 4762480          // loss partials [128]
#define OFF_WT 4762608           // conv wT 115,200 fl -> end ~19.5 MB

// ---------------- prep
#define NP1 (DDIM*EDIM*KW)          // 115200
#define NP2 (YLAB*DDIM)             // 1141888
#define NP3 (B*DDIM*(LP-LSEQ))      // 61440
#define NP4 (B*(LP-LSEQ)*DDIM)      // 61440
__global__ __launch_bounds__(256) void k_prep(const float* __restrict__ w, const float* __restrict__ U,
                                              float* __restrict__ wT, ushort* __restrict__ Ub,
                                              ushort* __restrict__ hT, ushort* __restrict__ hb){
    int i = blockIdx.x * 256 + threadIdx.x;
    if (i < NP1) {
        int k = i % KW, e = (i / KW) % EDIM, d = i / (KW * EDIM);
        wT[(k * EDIM + e) * DDIM + d] = w[i];
    }
    int i2 = i - NP1;
    if (i2 >= 0 && i2 < NP2) Ub[i2] = f2bf(U[i2]);
    int i3 = i - NP1 - NP2;
    if (i3 >= 0 && i3 < NP3) {
        int c = i3 % (LP - LSEQ), bd = i3 / (LP - LSEQ);
        hT[(size_t)bd * LP + LSEQ + c] = 0;
    }
    int i4 = i - NP1 - NP2 - NP3;
    if (i4 >= 0 && i4 < NP4) {
        int b = i4 / ((LP - LSEQ) * DDIM);
        int r = i4 % ((LP - LSEQ) * DDIM);
        int l = LSEQ + r / DDIM, d = r % DDIM;
        hb[((size_t)b * LP + l) * DDIM + d] = 0;
    }
}

// ---------------- fused embed + conv1d + tanh
#define CTL 20
__global__ __launch_bounds__(256) void k_conv(const int* __restrict__ x, const float* __restrict__ emb,
                                              const float* __restrict__ wT, const float* __restrict__ bias,
                                              ushort* __restrict__ hb, ushort* __restrict__ hT) {
    __shared__ float se[EDIM * 32];
    __shared__ ushort hstage[DDIM][CTL + 2];
    int blk = blockIdx.x;
    int b = blk / (LSEQ / CTL);
    int l0 = (blk % (LSEQ / CTL)) * CTL;
    int tid = threadIdx.x;
    for (int i = tid; i < (CTL + 8) * EDIM; i += 256) {
        int row = i / EDIM, e = i - row * EDIM;
        int l = l0 + row - 4;
        float v = 0.f;
        if (l >= 0 && l < LSEQ) {
            int tok = x[b * LSEQ + l];
            v = emb[(size_t)tok * EDIM + e];
        }
        se[e * 32 + row] = v;
    }
    __syncthreads();
    int d = tid & 127;
    int g = tid >> 7;
    float bv = bias[d];
    float acc[10];
#pragma unroll
    for (int li = 0; li < 10; li++) acc[li] = bv;
    for (int e = 0; e < EDIM; e++) {
        float r[20];
#pragma unroll
        for (int t2 = 0; t2 < 10; t2++) {
            float2 rr = *(const float2*)&se[e * 32 + g * 10 + 2 * t2];
            r[2 * t2] = rr.x; r[2 * t2 + 1] = rr.y;
        }
#pragma unroll
        for (int k = 0; k < KW; k++) {
            float wv = wT[(k * EDIM + e) * DDIM + d];
#pragma unroll
            for (int li = 0; li < 10; li++) acc[li] += r[li + k] * wv;
        }
    }
#pragma unroll
    for (int li = 0; li < 10; li++) {
        int l = l0 + g * 10 + li;
        ushort u = f2bf(tanhf(acc[li]));
        hb[((size_t)b * LP + l) * DDIM + d] = u;
        hstage[d][g * 10 + li] = u;
    }
    __syncthreads();
    int d2 = tid >> 1, half = tid & 1;
    size_t base = ((size_t)b * DDIM + d2) * LP + l0 + half * 10;
#pragma unroll
    for (int q = 0; q < 10; q++) hT[base + q] = hstage[d2][half * 10 + q];
}

// ---------------- softmax sums via MFMA: 128y x 128l blocks, XCD-swizzled
__global__ __launch_bounds__(256) void k_sums(const ushort* __restrict__ hb, const ushort* __restrict__ Ub,
                                              float* __restrict__ psum) {
    int wg = blockIdx.x;
    int b = wg & 7;
    int r = wg >> 3;
    int lblk = r % NLBS, yblk = r / NLBS;
    int l0 = lblk * 128, y0 = yblk * 128;
    int tid = threadIdx.x, w = tid >> 6, lane = tid & 63, g = lane >> 4, ln = lane & 15;
    int h = w >> 1, lh = w & 1;
    int y0w = y0 + h * 64;
    bf16x8 zf = {0, 0, 0, 0, 0, 0, 0, 0};
    bf16x8 au[4][4];
    bool vya[4];
#pragma unroll
    for (int yf = 0; yf < 4; yf++) {
        int ya = y0w + yf * 16 + ln;
        vya[yf] = ya < YLAB;
        const ushort* Ap = Ub + (size_t)(vya[yf] ? ya : 0) * DDIM + g * 8;
#pragma unroll
        for (int kk = 0; kk < 4; kk++) au[yf][kk] = vya[yf] ? *(const bf16x8*)(Ap + kk * 32) : zf;
    }
    f32x4 zero4 = {0.f, 0.f, 0.f, 0.f};
    const ushort* hbB = hb + (size_t)b * LP * DDIM;
    float ts[4][4] = {};
#pragma unroll
    for (int lt = 0; lt < 2; lt++) {
        int lw = l0 + (lt * 2 + lh) * 32;
        f32x4 acc[4][2];
#pragma unroll
        for (int yf = 0; yf < 4; yf++) { acc[yf][0] = zero4; acc[yf][1] = zero4; }
#pragma unroll
        for (int kk = 0; kk < 4; kk++) {
            bf16x8 bv0 = *(const bf16x8*)(hbB + (size_t)(lw + ln) * DDIM + kk * 32 + g * 8);
            bf16x8 bv1 = *(const bf16x8*)(hbB + (size_t)(lw + 16 + ln) * DDIM + kk * 32 + g * 8);
#pragma unroll
            for (int yf = 0; yf < 4; yf++) {
                acc[yf][0] = __builtin_amdgcn_mfma_f32_16x16x32_bf16(au[yf][kk], bv0, acc[yf][0], 0, 0, 0);
                acc[yf][1] = __builtin_amdgcn_mfma_f32_16x16x32_bf16(au[yf][kk], bv1, acc[yf][1], 0, 0, 0);
            }
        }
#pragma unroll
        for (int yf = 0; yf < 4; yf++)
#pragma unroll
            for (int fl = 0; fl < 2; fl++)
#pragma unroll
                for (int j = 0; j < 4; j++) {
                    int y = y0w + yf * 16 + g * 4 + j;
                    int l = lw + fl * 16 + ln;
                    bool v = (y < YLAB) && (l < LSEQ);
                    ts[yf][j] += v ? __expf(acc[yf][fl][j]) : 0.f;
                }
    }
#pragma unroll
    for (int yf = 0; yf < 4; yf++)
#pragma unroll
        for (int j = 0; j < 4; j++) {
            float t = ts[yf][j];
            t += __shfl_xor(t, 1, 64); t += __shfl_xor(t, 2, 64);
            t += __shfl_xor(t, 4, 64); t += __shfl_xor(t, 8, 64);
            ts[yf][j] = t;
        }
    __shared__ float psl[2][128];
    if (ln == 0) {
#pragma unroll
        for (int yf = 0; yf < 4; yf++)
#pragma unroll
            for (int j = 0; j < 4; j++)
                psl[lh][h * 64 + yf * 16 + g * 4 + j] = ts[yf][j];
    }
    __syncthreads();
    if (tid < 128) {
        int y = y0 + tid;
        if (y < YLAB) psum[(size_t)lblk * BYTOT + b * YLAB + y] = psl[0][tid] + psl[1][tid];
    }
}

// ---------------- rinv
__global__ __launch_bounds__(256) void k_rinv(const float* __restrict__ psum, float* __restrict__ rinv) {
    int i = blockIdx.x * 256 + threadIdx.x;
    if (i >= BYTOT) return;
    float s = 0.f;
#pragma unroll
    for (int j = 0; j < NLBS; j++) s += psum[(size_t)j * BYTOT + i];
    rinv[i] = 1.f / s;
}

// ---------------- fused pool: staged scores + deferred-store alpha (et dbuf) + pool MFMA + logits
__global__ __launch_bounds__(256) void k_pool(const ushort* __restrict__ hb, const ushort* __restrict__ hT,
                                              const ushort* __restrict__ Ub, const float* __restrict__ rinv,
                                              const float* __restrict__ fw, const float* __restrict__ fb,
                                              float* __restrict__ alpha, float* __restrict__ yhat,
                                              float* __restrict__ logits) {
    __shared__ ushort hbs[32 * 128];       // 8 KB
    __shared__ ushort hts[128 * 40];       // 10 KB
    __shared__ ushort et[2][4][16 * 44];   // 11 KB (double-buffered bf16 alpha tile = pool A-frag)
    int wg = blockIdx.x;
    int b = wg & 7;
    int y0 = (wg >> 3) * 64;
    int tid = threadIdx.x, w = tid >> 6, lane = tid & 63, g = lane >> 4, ln = lane & 15;
    int y0w = y0 + w * 16;
    bf16x8 zf = {0, 0, 0, 0, 0, 0, 0, 0};
    int ya = y0w + ln;
    bool vya = ya < YLAB;
    const ushort* Ap = Ub + (size_t)(vya ? ya : 0) * DDIM + g * 8;
    bf16x8 au[4];
#pragma unroll
    for (int kk = 0; kk < 4; kk++) au[kk] = vya ? *(const bf16x8*)(Ap + kk * 32) : zf;
    float rvl = vya ? rinv[b * YLAB + ya] : 0.f;
    f32x4 zero4 = {0.f, 0.f, 0.f, 0.f};
    f32x4 accm[8];
#pragma unroll
    for (int fd = 0; fd < 8; fd++) accm[fd] = zero4;

    int s0 = tid, s1 = tid + 256;
    const ushort* hbB = hb + (size_t)b * LP * DDIM;
    const ushort* htB = hT + (size_t)b * DDIM * LP;
    int l_a = s0 >> 4, sg_a = s0 & 15, l_b = s1 >> 4, sg_b = s1 & 15;
    int d_a = s0 >> 2, q_a = s0 & 3, d_b = s1 >> 2, q_b = s1 & 3;
    int wsg_a = sg_a ^ (l_a & 7), wsg_b = sg_b ^ (l_b & 7);
    u16x8 rhb0, rhb1, rht0, rht1;
    rhb0 = *(const u16x8*)(hbB + (size_t)l_a * DDIM + sg_a * 8);
    rhb1 = *(const u16x8*)(hbB + (size_t)l_b * DDIM + sg_b * 8);
    rht0 = *(const u16x8*)(htB + (size_t)d_a * LP + q_a * 8);
    rht1 = *(const u16x8*)(htB + (size_t)d_b * LP + q_b * 8);

    float* aB = alpha + (size_t)b * YLAB * LSEQ;

    // deferred alpha store of tile [ls, ls+32) from et[p]
    auto store_tile = [&](int p, int ls) {
        if (ls >= LSEQ) return;
        if (ls + 32 <= LSEQ) {
#pragma unroll
            for (int i = 0; i < 8; i++) {
                int r2 = i * 2 + (lane >> 5);
                int c = lane & 31;
                int y = y0w + r2;
                if (y < YLAB) aB[(size_t)y * LSEQ + ls + c] = bf2f(et[p][w][r2 * 44 + c]);
            }
        } else {
#pragma unroll
            for (int i = 0; i < 8; i++) {
                int r2 = i * 2 + (lane >> 5);
                int c = lane & 31;
                int y = y0w + r2;
                int l = ls + c;
                if (y < YLAB && l < LSEQ) aB[(size_t)y * LSEQ + l] = bf2f(et[p][w][r2 * 44 + c]);
            }
        }
    };

    for (int l0 = 0; l0 < LP; l0 += 32) {
        int p = (l0 >> 5) & 1;
        *(u16x8*)&hbs[l_a * DDIM + wsg_a * 8] = rhb0;
        *(u16x8*)&hbs[l_b * DDIM + wsg_b * 8] = rhb1;
        *(u16x8*)&hts[d_a * 40 + q_a * 8] = rht0;
        *(u16x8*)&hts[d_b * 40 + q_b * 8] = rht1;
        __syncthreads();
        if (l0 + 32 < LP) {
            int ln0 = l0 + 32;
            rhb0 = *(const u16x8*)(hbB + (size_t)(ln0 + l_a) * DDIM + sg_a * 8);
            rhb1 = *(const u16x8*)(hbB + (size_t)(ln0 + l_b) * DDIM + sg_b * 8);
            rht0 = *(const u16x8*)(htB + (size_t)d_a * LP + ln0 + q_a * 8);
            rht1 = *(const u16x8*)(htB + (size_t)d_b * LP + ln0 + q_b * 8);
        }
        // issue previous tile's alpha stores — they drain during this tile's compute
        if (l0 > 0) store_tile(p ^ 1, l0 - 32);
        // scores swapped: sc[fl][j] = s[y=y0w+ln][l=l0+fl*16+g*4+j]
        f32x4 sc[2];
        sc[0] = zero4; sc[1] = zero4;
#pragma unroll
        for (int kk = 0; kk < 4; kk++)
#pragma unroll
            for (int fl = 0; fl < 2; fl++) {
                int lrow = fl * 16 + ln;
                int slotr = (kk * 4 + g) ^ (lrow & 7);
                bf16x8 bv = *(const bf16x8*)&hbs[lrow * DDIM + slotr * 8];
                sc[fl] = __builtin_amdgcn_mfma_f32_16x16x32_bf16(bv, au[kk], sc[fl], 0, 0, 0);
            }
        // exp*rinv -> et[p] (bf16): alpha tile = pool A-frag
#pragma unroll
        for (int fl = 0; fl < 2; fl++) {
            float an0 = __expf(sc[fl][0]) * rvl;
            float an1 = __expf(sc[fl][1]) * rvl;
            float an2 = __expf(sc[fl][2]) * rvl;
            float an3 = __expf(sc[fl][3]) * rvl;
            unsigned long long pk =
                (unsigned long long)f2bf(an0) | ((unsigned long long)f2bf(an1) << 16) |
                ((unsigned long long)f2bf(an2) << 32) | ((unsigned long long)f2bf(an3) << 48);
            *(unsigned long long*)&et[p][w][ln * 44 + fl * 16 + g * 4] = pk;
        }
        // pool MFMA
        bf16x8 af = *(const bf16x8*)&et[p][w][ln * 44 + g * 8];
#pragma unroll
        for (int fd = 0; fd < 8; fd++) {
            bf16x8 bt = *(const bf16x8*)&hts[(fd * 16 + ln) * 40 + g * 8];
            accm[fd] = __builtin_amdgcn_mfma_f32_16x16x32_bf16(af, bt, accm[fd], 0, 0, 0);
        }
        __syncthreads();
    }
    // flush final tile's stores
    store_tile(((LP - 32) >> 5) & 1, LP - 32);
    // fused logits epilogue
    float lp[4] = {0.f, 0.f, 0.f, 0.f};
#pragma unroll
    for (int j = 0; j < 4; j++) {
        int yr = y0w + g * 4 + j;
        bool vr = yr < YLAB;
#pragma unroll
        for (int fd = 0; fd < 8; fd++) {
            float fwv = vr ? fw[(size_t)yr * DDIM + fd * 16 + ln] : 0.f;
            lp[j] += accm[fd][j] * fwv;
        }
    }
#pragma unroll
    for (int j = 0; j < 4; j++) {
        float t = lp[j];
        t += __shfl_xor(t, 1, 64); t += __shfl_xor(t, 2, 64);
        t += __shfl_xor(t, 4, 64); t += __shfl_xor(t, 8, 64);
        lp[j] = t;
    }
    if (ln == 0) {
#pragma unroll
        for (int j = 0; j < 4; j++) {
            int yr = y0w + g * 4 + j;
            if (yr < YLAB) {
                float lg = lp[j] + fb[yr];
                int idx = b * YLAB + yr;
                logits[idx] = lg;
                yhat[idx] = 1.f / (1.f + expf(-lg));
            }
        }
    }
}

// ---------------- BCE partials (70 blocks) + finalize
__global__ __launch_bounds__(256) void k_loss1(const float* __restrict__ logits, const float* __restrict__ target,
                                               float* __restrict__ partials) {
    int tid = threadIdx.x;
    int base = blockIdx.x * 1024;
    float sum = 0.f;
#pragma unroll
    for (int q = 0; q < 4; q++) {
        int i = base + q * 256 + tid;
        if (i < BYTOT) {
            float z = logits[i], t = target[i];
            sum += fmaxf(z, 0.f) - z * t + log1pf(expf(-fabsf(z)));
        }
    }
    for (int o = 32; o > 0; o >>= 1) sum += __shfl_down(sum, o, 64);
    __shared__ float red[4];
    if ((tid & 63) == 0) red[tid >> 6] = sum;
    __syncthreads();
    if (tid == 0) partials[blockIdx.x] = red[0] + red[1] + red[2] + red[3];
}

__global__ __launch_bounds__(128) void k_loss2(const float* __restrict__ partials, float* __restrict__ out_loss) {
    int tid = threadIdx.x;
    float s = (tid < 70) ? partials[tid] : 0.f;
    for (int o = 32; o > 0; o >>= 1) s += __shfl_down(s, o, 64);
    __shared__ float red[2];
    if ((tid & 63) == 0) red[tid >> 6] = s;
    __syncthreads();
    if (tid == 0) out_loss[0] = (red[0] + red[1]) / (float)BYTOT;
}

extern "C" void kernel_launch(void* const* d_in, const int* in_sizes, int n_in,
                              void* d_out, int out_size, void* d_ws, size_t ws_size,
                              hipStream_t stream) {
    const int* x = (const int*)d_in[0];
    const float* target = (const float*)d_in[1];
    const float* emb = (const float*)d_in[2];
    const float* conv_w = (const float*)d_in[3];
    const float* conv_b = (const float*)d_in[4];
    const float* U = (const float*)d_in[5];
    const float* fw = (const float*)d_in[6];
    const float* fb = (const float*)d_in[7];

    float* out = (float*)d_out;
    float* yhat = out;
    float* loss = out + BYTOT;
    float* alpha = out + BYTOT + 1;

    float* ws = (float*)d_ws;
    ushort* hb = (ushort*)(ws + OFF_HB);
    ushort* hT = (ushort*)(ws + OFF_HT);
    ushort* Ub = (ushort*)(ws + OFF_UB);
    float* psum = ws + OFF_PS;
    float* rinv = ws + OFF_RI;
    float* logits = ws + OFF_LG;
    float* lpart = ws + OFF_LSP;
    float* wT = ws + OFF_WT;

    k_prep<<<(NP1 + NP2 + NP3 + NP4 + 255) / 256, 256, 0, stream>>>(conv_w, U, wT, Ub, hT, hb);
    k_conv<<<B * (LSEQ / CTL), 256, 0, stream>>>(x, emb, wT, conv_b, hb, hT);
    k_sums<<<NYB * NLBS * B, 256, 0, stream>>>(hb, Ub, psum);
    k_rinv<<<(BYTOT + 255) / 256, 256, 0, stream>>>(psum, rinv);
    k_pool<<<NPB * B, 256, 0, stream>>>(hb, hT, Ub, rinv, fw, fb, alpha, yhat, logits);
    k_loss1<<<70, 256, 0, stream>>>(logits, target, lpart);
    k_loss2<<<1, 128, 0, stream>>>(lpart, loss);
}